// Round 8
// baseline (126.210 us; speedup 1.0000x reference)
//
#include <hip/hip_runtime.h>
#include <hip/hip_bf16.h>

#define VOCAB 100000
#define EMBED 64
#define NPAIR (1024 * 50)   // B*S (51200)
#define KIDS  20

typedef int   int4v   __attribute__((ext_vector_type(4)));

static __device__ inline ushort f2bf(float f) {
    __hip_bfloat16 h = __float2bfloat16(f);   // RN conversion
    return __builtin_bit_cast(ushort, h);
}
static __device__ inline float bf2f(ushort u) {
    unsigned int v = ((unsigned int)u) << 16;  // exact widening
    return __builtin_bit_cast(float, v);
}

// ---------------------------------------------------------------------------
// Kernel 1: transpose+convert W [E=64, V] fp32 -> 4 dim-sliced bf16 tables:
// Wt[s][v][16], s=0..3. Each slice = V*16*2B = 3.2 MB (fits one XCD L2).
// W read once -> nontemporal.
// ---------------------------------------------------------------------------
__global__ __launch_bounds__(256) void convert_w(const float* __restrict__ W,
                                                 ushort* __restrict__ Wt) {
    __shared__ float tile[64][65];   // +1 pad
    const int v0 = blockIdx.x * 64;
    const int tx = threadIdx.x & 63;   // v offset within tile
    const int ty = threadIdx.x >> 6;   // 0..3
    const int v = v0 + tx;
    if (v < VOCAB) {
        #pragma unroll
        for (int e = ty; e < 64; e += 4) {
            tile[tx][e] = __builtin_nontemporal_load(&W[(size_t)e * VOCAB + v]);
        }
    }
    __syncthreads();
    const int r  = threadIdx.x >> 2;          // v offset within tile
    const int c0 = (threadIdx.x & 3) * 16;    // dim base == slice*16
    if (v0 + r < VOCAB) {
        uint pk[8];
        #pragma unroll
        for (int i = 0; i < 8; i++) {
            ushort lo = f2bf(tile[r][c0 + 2 * i + 0]);
            ushort hi = f2bf(tile[r][c0 + 2 * i + 1]);
            pk[i] = (uint)lo | ((uint)hi << 16);
        }
        // Slice-major layout: slice (c0/16), row (v0+r), 16 dims = 32B.
        ushort* dst = Wt + (size_t)(c0 >> 4) * VOCAB * 16 + (size_t)(v0 + r) * 16;
        uint4* outv = (uint4*)dst;
        outv[0] = make_uint4(pk[0], pk[1], pk[2], pk[3]);
        outv[1] = make_uint4(pk[4], pk[5], pk[6], pk[7]);
    }
}

// ---------------------------------------------------------------------------
// Kernel 2: dim-sliced gather. Slice s pinned to XCDs {2s,2s+1} via the
// default round-robin blockIdx%8 -> XCD mapping, so each XCD's L2 working
// set is one 3.2MB slice (resident). 16 lanes per pair (lane&15 = dim),
// 4 pairs per wave instruction; 20 ushort row-slice loads per pair-group.
// ids nt (streamed 4x), out nt (streamed once per slice).
// ---------------------------------------------------------------------------
__global__ __launch_bounds__(256) void gather_sliced(const int* __restrict__ ids,
                                                     const ushort* __restrict__ Wt,
                                                     const float* __restrict__ bias,
                                                     float* __restrict__ out) {
    const int b    = blockIdx.x;
    const int xcd  = b & 7;            // assumed XCD via round-robin dispatch
    const int xi   = b >> 3;           // 0..1599 within XCD
    const int s    = xcd >> 1;         // dim-slice 0..3
    const int half = xcd & 1;          // which half of the pairs
    const int wv   = (int)(threadIdx.x >> 6);  // wave in block 0..3
    const int lane = (int)(threadIdx.x & 63);
    const int g    = lane >> 4;        // pair sub-index 0..3
    const int d    = lane & 15;        // dim within slice

    const int pair = half * (NPAIR / 2) + xi * 16 + wv * 4 + g;
    const ushort* tbl = Wt + (size_t)s * VOCAB * 16;

    const int4v* idv = (const int4v*)(ids + (size_t)pair * KIDS);
    float acc = 0.f;
    #pragma unroll
    for (int k = 0; k < 5; k++) {
        int4v q = __builtin_nontemporal_load(&idv[k]);
        acc += bf2f(tbl[(((uint)q.x) << 4) + d]);
        acc += bf2f(tbl[(((uint)q.y) << 4) + d]);
        acc += bf2f(tbl[(((uint)q.z) << 4) + d]);
        acc += bf2f(tbl[(((uint)q.w) << 4) + d]);
    }
    acc += bias[s * 16 + d];
    __builtin_nontemporal_store(acc, &out[(size_t)pair * 64 + s * 16 + d]);
}

// ---------------------------------------------------------------------------
// Fallback (ws too small): direct uncoalesced gather on native W [E, V].
// ---------------------------------------------------------------------------
__global__ __launch_bounds__(256) void gather_direct(const int* __restrict__ ids,
                                                     const float* __restrict__ W,
                                                     const float* __restrict__ bias,
                                                     float* __restrict__ out) {
    const int wave = (blockIdx.x * blockDim.x + threadIdx.x) >> 6;
    const int lane = threadIdx.x & 63;
    if (wave >= NPAIR) return;

    const int* myids = ids + (size_t)wave * KIDS;
    float acc = bias[lane];
    #pragma unroll
    for (int k = 0; k < KIDS; k++) {
        int id = myids[k];
        acc += W[(size_t)lane * VOCAB + id];
    }
    out[(size_t)wave * 64 + lane] = acc;
}

extern "C" void kernel_launch(void* const* d_in, const int* in_sizes, int n_in,
                              void* d_out, int out_size, void* d_ws, size_t ws_size,
                              hipStream_t stream) {
    const int*   ids  = (const int*)d_in[0];    // [B,S,K] int32
    const float* W    = (const float*)d_in[1];  // [E, V] fp32
    const float* bias = (const float*)d_in[2];  // [E] fp32
    float*       out  = (float*)d_out;          // [B,S,E] fp32

    const size_t wt_bytes = (size_t)VOCAB * EMBED * sizeof(ushort);  // 12.8 MB

    if (ws_size >= wt_bytes) {
        ushort* Wt = (ushort*)d_ws;
        const int tr_blocks = (VOCAB + 63) / 64;   // 1563
        convert_w<<<tr_blocks, 256, 0, stream>>>(W, Wt);
        // 8 XCD groups x 1600 blocks; each block: 4 waves x 4 pairs = 16 pairs
        // of one dim-slice. 12800 blocks total = 4 slices x 51200 pairs.
        gather_sliced<<<12800, 256, 0, stream>>>(ids, Wt, bias, out);
    } else {
        const int g_blocks = (NPAIR * 64 + 255) / 256;
        gather_direct<<<g_blocks, 256, 0, stream>>>(ids, W, bias, out);
    }
}